// Round 2
// baseline (25337.704 us; speedup 1.0000x reference)
//
#include <hip/hip_runtime.h>
#include <hip/hip_bf16.h>
#include <math.h>

#define B_ 64
#define T_ 1024
#define D_ 512
#define H_ 512
#define M_ 256
#define CC 63
#define SS 64
#define INV_SQRT_2PI 0.3989422804014327f

typedef __attribute__((ext_vector_type(8))) short short8v;
typedef __attribute__((ext_vector_type(4))) float f32x4;

static __device__ __forceinline__ float bf2f(unsigned short u) {
    unsigned int x = ((unsigned int)u) << 16;
    return __uint_as_float(x);
}
static __device__ __forceinline__ unsigned short f2bf(float f) {
    unsigned int x = __float_as_uint(f);
    unsigned int r = (x + 0x7fff + ((x >> 16) & 1)) >> 16;
    return (unsigned short)r;
}
static __device__ __forceinline__ float sigm(float x) {
    return 1.f / (1.f + __expf(-x));
}

// grid barrier: monotone counter, agent scope. bar zeroed by hipMemsetAsync per launch.
static __device__ __forceinline__ void gbar(int* bar, int& tgt) {
    tgt += 256;
    __syncthreads();                       // drains vmcnt: all block's writes in L2
    if (threadIdx.x == 0) {
        __builtin_amdgcn_fence(__ATOMIC_RELEASE, "agent");   // wb local XCD L2
        __hip_atomic_fetch_add(bar, 1, __ATOMIC_RELAXED, __HIP_MEMORY_SCOPE_AGENT);
        while (__hip_atomic_load(bar, __ATOMIC_RELAXED, __HIP_MEMORY_SCOPE_AGENT) < tgt) {
            __builtin_amdgcn_s_sleep(2);
        }
        __builtin_amdgcn_fence(__ATOMIC_ACQUIRE, "agent");   // inv L1 + L2 shared lines
    }
    __syncthreads();
}

// ---------------- prologue kernels ----------------

// f32 -> bf16 (used for listener and psi weights)
__global__ __launch_bounds__(256) void k_conv(const float* __restrict__ src,
        unsigned short* __restrict__ dst, int n4) {
    int stride = gridDim.x * 256;
    for (int i = blockIdx.x * 256 + threadIdx.x; i < n4; i += stride) {
        float4 v = ((const float4*)src)[i];
        ushort4 o;
        o.x = f2bf(v.x); o.y = f2bf(v.y); o.z = f2bf(v.z); o.w = f2bf(v.w);
        ((ushort4*)dst)[i] = o;
    }
}

// MFMA bf16 GEMM: clT[b*256+m][t] = bf16(relu(sum_d Lbf[p][d]*psibf[m][d] + psib[m])), p=b*1024+t
__global__ __launch_bounds__(256) void k_gemm_mfma(
        const unsigned short* __restrict__ Abf,   // [65536][512] bf16
        const unsigned short* __restrict__ Bbf,   // [256][512] bf16
        const float* __restrict__ psib,
        unsigned short* __restrict__ clT) {
    __shared__ unsigned short As[64 * 40];   // 64 rows x 32 bf16, stride 40 (80B, 16B aligned)
    __shared__ unsigned short Bs[64 * 40];
    __shared__ unsigned short Os[64 * 72];   // out staging [m][t], stride 72 (144B, 16B aligned)
    int tid = threadIdx.x;
    int p0 = (blockIdx.x >> 2) * 64;
    int m0 = (blockIdx.x & 3) * 64;
    int w = tid >> 6, l = tid & 63;
    int wp = (w & 1) * 32, wm = (w >> 1) * 32;
    f32x4 acc[2][2] = {};
    int srow = tid >> 2, sc = (tid & 3) * 8;
    for (int k0 = 0; k0 < 512; k0 += 32) {
        __syncthreads();
        *(short8v*)&As[srow * 40 + sc] = *(const short8v*)&Abf[(size_t)(p0 + srow) * 512 + k0 + sc];
        *(short8v*)&Bs[srow * 40 + sc] = *(const short8v*)&Bbf[(size_t)(m0 + srow) * 512 + k0 + sc];
        __syncthreads();
        int koff = (l >> 4) * 8;
        int rlo = l & 15;
        short8v a0 = *(short8v*)&As[(wp + rlo) * 40 + koff];
        short8v a1 = *(short8v*)&As[(wp + 16 + rlo) * 40 + koff];
        short8v b0 = *(short8v*)&Bs[(wm + rlo) * 40 + koff];
        short8v b1 = *(short8v*)&Bs[(wm + 16 + rlo) * 40 + koff];
        acc[0][0] = __builtin_amdgcn_mfma_f32_16x16x32_bf16(a0, b0, acc[0][0], 0, 0, 0);
        acc[0][1] = __builtin_amdgcn_mfma_f32_16x16x32_bf16(a0, b1, acc[0][1], 0, 0, 0);
        acc[1][0] = __builtin_amdgcn_mfma_f32_16x16x32_bf16(a1, b0, acc[1][0], 0, 0, 0);
        acc[1][1] = __builtin_amdgcn_mfma_f32_16x16x32_bf16(a1, b1, acc[1][1], 0, 0, 0);
    }
    __syncthreads();
#pragma unroll
    for (int pi = 0; pi < 2; ++pi)
#pragma unroll
        for (int mi = 0; mi < 2; ++mi)
#pragma unroll
            for (int r = 0; r < 4; ++r) {
                int tl = wp + pi * 16 + (l >> 4) * 4 + r;   // p-local (C row)
                int ml = wm + mi * 16 + (l & 15);           // m-local (C col)
                float v = fmaxf(acc[pi][mi][r] + psib[m0 + ml], 0.f);
                Os[ml * 72 + tl] = f2bf(v);
            }
    __syncthreads();
    int b = p0 >> 10, t0 = p0 & 1023;
    int mm = tid >> 2, c16 = (tid & 3) * 16;
    short8v v0 = *(short8v*)&Os[mm * 72 + c16];
    short8v v1 = *(short8v*)&Os[mm * 72 + c16 + 8];
    size_t base = ((size_t)(b * 256 + m0 + mm)) * 1024 + t0 + c16;
    *(short8v*)&clT[base] = v0;
    *(short8v*)&clT[base + 8] = v1;
}

// fallback f32 GEMM (if ws too small for bf16 listener copy)
__global__ __launch_bounds__(256) void k_gemm(const float* __restrict__ Lf,
        const float* __restrict__ psiw, const float* __restrict__ psib,
        unsigned short* __restrict__ clT) {
    __shared__ float At[64 * 65];
    __shared__ float Bt[64 * 65];
    int tid = threadIdx.x;
    int pt = blockIdx.x >> 2;
    int mt = blockIdx.x & 3;
    int p0 = pt * 64, m0 = mt * 64;
    int tp = tid >> 4, tm = tid & 15;
    float acc[4][4] = {{0.f}};
    for (int k0 = 0; k0 < 512; k0 += 64) {
        __syncthreads();
        for (int i = 0; i < 16; ++i) {
            int lidx = i * 256 + tid;
            int r = lidx >> 6, c = lidx & 63;
            At[r * 65 + c] = Lf[(size_t)(p0 + r) * 512 + k0 + c];
            Bt[r * 65 + c] = psiw[(size_t)(m0 + r) * 512 + k0 + c];
        }
        __syncthreads();
        for (int dk = 0; dk < 64; ++dk) {
            float av[4], bv[4];
#pragma unroll
            for (int i = 0; i < 4; ++i) av[i] = At[(4 * tp + i) * 65 + dk];
#pragma unroll
            for (int j = 0; j < 4; ++j) bv[j] = Bt[(4 * tm + j) * 65 + dk];
#pragma unroll
            for (int i = 0; i < 4; ++i)
#pragma unroll
                for (int j = 0; j < 4; ++j)
                    acc[i][j] = fmaf(av[i], bv[j], acc[i][j]);
        }
    }
#pragma unroll
    for (int i = 0; i < 4; ++i) {
        int p = p0 + 4 * tp + i;
        int b = p >> 10, t = p & 1023;
#pragma unroll
        for (int j = 0; j < 4; ++j) {
            int m = m0 + 4 * tm + j;
            float v = fmaxf(acc[i][j] + psib[m], 0.f);
            clT[((size_t)(b * 256 + m)) * 1024 + t] = f2bf(v);
        }
    }
}

// ---------------- persistent mega kernel ----------------

static __device__ __forceinline__ void charpred(int b, int ps,
        const float* __restrict__ h1buf, const float* __restrict__ ctxT,
        const float* __restrict__ charw, const float* __restrict__ charb,
        float* __restrict__ preds, float* cpx) {
    int tid = threadIdx.x;
    for (int i = tid; i < 1024; i += 256)
        cpx[i] = (i < 512) ? h1buf[i * 64 + b] : ctxT[(i - 512) * 64 + b];
    __syncthreads();
    if (tid < 64) {
        float logit = -1e30f;
        if (tid < 63) {
            float a = charb[tid];
            const float4* wr = (const float4*)(charw + (size_t)tid * 1024);
            for (int u4 = 0; u4 < 256; ++u4) {
                float4 w4 = wr[u4];
                a = fmaf(cpx[4 * u4 + 0], w4.x, a);
                a = fmaf(cpx[4 * u4 + 1], w4.y, a);
                a = fmaf(cpx[4 * u4 + 2], w4.z, a);
                a = fmaf(cpx[4 * u4 + 3], w4.w, a);
            }
            logit = a;
        }
        float mx = logit;
        for (int o = 32; o > 0; o >>= 1) mx = fmaxf(mx, __shfl_xor(mx, o, 64));
        float ex2 = (tid < 63) ? __expf(logit - mx) : 0.f;
        float sum = ex2;
        for (int o = 32; o > 0; o >>= 1) sum += __shfl_xor(sum, o, 64);
        if (tid < 63)
            preds[((size_t)ps * B_ + b) * CC + tid] = logit - mx - __logf(sum);
    }
    __syncthreads();
}

__global__ __launch_bounds__(256, 2) void k_mega(
        const float* __restrict__ Lf, const unsigned short* __restrict__ Lbf, int useBf,
        const float* __restrict__ gt,
        const float* __restrict__ phiw, const float* __restrict__ phib,
        const float* __restrict__ wih0, const float* __restrict__ whh0,
        const float* __restrict__ bih0, const float* __restrict__ bhh0,
        const float* __restrict__ wih1, const float* __restrict__ whh1,
        const float* __restrict__ bih1, const float* __restrict__ bhh1,
        const float* __restrict__ charw, const float* __restrict__ charb,
        const unsigned short* __restrict__ clT,
        float* gtT, float* h0, float* c0, float* h1, float* c1, float* h1b,
        float* ctxT, float* energy, float* vbuf, float* pmax, float* psum,
        int* colZero, int* bar,
        float* preds, float* atts) {
    __shared__ float smem[5120];   // 20KB, reused per phase
    int tid = threadIdx.x;
    int blk = blockIdx.x;
    int barTgt = 0;

    // ---- INIT ----
    if (blk < 64) {
        int s0 = blk;
        for (int r = tid; r < CC * 64; r += 256) {
            int k = r >> 6, b = r & 63;
            gtT[s0 * (CC * 64) + r] = gt[(b * SS + s0) * CC + k];
        }
    } else if (blk < 192) {
        int idx = (blk - 64) * 256 + tid;   // 0..32767
        h0[idx] = 0.f; c0[idx] = 0.f; h1[idx] = 0.f; c1[idx] = 0.f;
        ctxT[idx] = Lf[(size_t)(idx & 63) * (T_ * D_) + (idx >> 6)];
    }
    gbar(bar, barTgt);

    for (int s = 0; s < SS; ++s) {
        int pin = s & 1;
        const float* h0in = h0 + pin * 32768;
        float* h0out = h0 + (1 - pin) * 32768;
        const float* h1in = h1 + pin * 32768;
        float* h1out = h1 + (1 - pin) * 32768;

        // ---- phase A: LSTM0 ----
        {
            float* sm = smem;
            float* ex = smem + 4096;
            int b = tid & 63, g = tid >> 6;
            int u0 = blk * 2;
            int j0 = g * 512 + u0;
            float acc0 = bih0[j0] + bhh0[j0];
            float acc1 = bih0[j0 + 1] + bhh0[j0 + 1];
            const float* w0r = wih0 + (size_t)j0 * 575;
            const float* w1r = wih0 + (size_t)(j0 + 1) * 575;
            const float* v0r = whh0 + (size_t)j0 * 512;
            const float* v1r = whh0 + (size_t)(j0 + 1) * 512;
            for (int k0 = 0; k0 < 1088; k0 += 64) {
                __syncthreads();
                for (int i = 0; i < 16; ++i) {
                    int lidx = i * 256 + tid;
                    int k = k0 + (lidx >> 6);
                    int bb = lidx & 63;
                    float v;
                    if (k < 63) {
                        v = (s > 0) ? gtT[(s - 1) * (CC * 64) + k * 64 + bb]
                                    : ((k == 0) ? 1.f : 0.f);
                    } else if (k < 575) {
                        v = ctxT[(k - 63) * 64 + bb];
                    } else if (k < 1087) {
                        v = h0in[(k - 575) * 64 + bb];
                    } else v = 0.f;
                    sm[lidx] = v;
                }
                __syncthreads();
                for (int kk = 0; kk < 64; ++kk) {
                    int k = k0 + kk;
                    float xv = sm[kk * 64 + b];
                    float w0, w1;
                    if (k < 575)       { w0 = w0r[k];       w1 = w1r[k]; }
                    else if (k < 1087) { w0 = v0r[k - 575]; w1 = v1r[k - 575]; }
                    else               { w0 = 0.f;          w1 = 0.f; }
                    acc0 = fmaf(xv, w0, acc0);
                    acc1 = fmaf(xv, w1, acc1);
                }
            }
            __syncthreads();
            ex[(g * 2 + 0) * 64 + b] = acc0;
            ex[(g * 2 + 1) * 64 + b] = acc1;
            __syncthreads();
            if (tid < 128) {
                int b2 = tid & 63, i = tid >> 6, u = u0 + i;
                float gi = ex[(0 * 2 + i) * 64 + b2];
                float gf = ex[(1 * 2 + i) * 64 + b2];
                float gg = ex[(2 * 2 + i) * 64 + b2];
                float go = ex[(3 * 2 + i) * 64 + b2];
                float cv = c0[u * 64 + b2];
                float cn = sigm(gf) * cv + sigm(gi) * tanhf(gg);
                float hn = sigm(go) * tanhf(cn);
                c0[u * 64 + b2] = cn;
                h0out[u * 64 + b2] = hn;
            }
            if (blk == 0) {
                __syncthreads();
                for (int i = tid; i < 1024; i += 256) colZero[i] = 1;
            }
        }
        gbar(bar, barTgt);

        // ---- phase B: LSTM1 ----
        {
            float* sm = smem;
            float* ex = smem + 4096;
            int b = tid & 63, g = tid >> 6;
            int u0 = blk * 2;
            int j0 = g * 512 + u0;
            float acc0 = bih1[j0] + bhh1[j0];
            float acc1 = bih1[j0 + 1] + bhh1[j0 + 1];
            const float* w0r = wih1 + (size_t)j0 * 512;
            const float* w1r = wih1 + (size_t)(j0 + 1) * 512;
            const float* v0r = whh1 + (size_t)j0 * 512;
            const float* v1r = whh1 + (size_t)(j0 + 1) * 512;
            for (int k0 = 0; k0 < 1024; k0 += 64) {
                __syncthreads();
                for (int i = 0; i < 16; ++i) {
                    int lidx = i * 256 + tid;
                    int k = k0 + (lidx >> 6);
                    int bb = lidx & 63;
                    sm[lidx] = (k < 512) ? h0out[k * 64 + bb] : h1in[(k - 512) * 64 + bb];
                }
                __syncthreads();
                for (int kk = 0; kk < 64; ++kk) {
                    int k = k0 + kk;
                    float xv = sm[kk * 64 + b];
                    float w0, w1;
                    if (k < 512) { w0 = w0r[k];       w1 = w1r[k]; }
                    else         { w0 = v0r[k - 512]; w1 = v1r[k - 512]; }
                    acc0 = fmaf(xv, w0, acc0);
                    acc1 = fmaf(xv, w1, acc1);
                }
            }
            __syncthreads();
            ex[(g * 2 + 0) * 64 + b] = acc0;
            ex[(g * 2 + 1) * 64 + b] = acc1;
            __syncthreads();
            if (tid < 128) {
                int b2 = tid & 63, i = tid >> 6, u = u0 + i;
                float gi = ex[(0 * 2 + i) * 64 + b2];
                float gf = ex[(1 * 2 + i) * 64 + b2];
                float gg = ex[(2 * 2 + i) * 64 + b2];
                float go = ex[(3 * 2 + i) * 64 + b2];
                float cv = c1[u * 64 + b2];
                float cn = sigm(gf) * cv + sigm(gi) * tanhf(gg);
                float hn = sigm(go) * tanhf(cn);
                c1[u * 64 + b2] = cn;
                h1out[u * 64 + b2] = hn;
                h1b[b2 * 512 + u] = hn;       // by-batch layout for phase C
            }
        }
        gbar(bar, barTgt);

        // ---- phase C: comp_dec + energy ----
        {
            int b = blk >> 2, q = blk & 3, t0g = q * 256;
            float* xs = smem;
            float* cd = smem + 512;
            xs[tid] = h1b[b * 512 + tid];
            xs[tid + 256] = h1b[b * 512 + 256 + tid];
            __syncthreads();
            float a = phib[tid];
            const float4* wr = (const float4*)(phiw + (size_t)tid * 512);
            for (int u4 = 0; u4 < 128; ++u4) {
                float4 w4 = wr[u4];
                a = fmaf(xs[4 * u4 + 0], w4.x, a);
                a = fmaf(xs[4 * u4 + 1], w4.y, a);
                a = fmaf(xs[4 * u4 + 2], w4.z, a);
                a = fmaf(xs[4 * u4 + 3], w4.w, a);
            }
            cd[tid] = fmaxf(a, 0.f);
            __syncthreads();
            int t = t0g + tid;
            float e = 0.f;
            const unsigned short* base = clT + (size_t)b * (256 * 1024) + t;
#pragma unroll 4
            for (int m = 0; m < 256; ++m)
                e = fmaf(cd[m], bf2f(base[(size_t)m * 1024]), e);
            energy[b * 1024 + t] = e;
            if (e != 0.f) colZero[t] = 0;
        }
        gbar(bar, barTgt);

        // ---- phase D1: copula stats + vals + partial softmax (+ char-pred s-1) ----
        {
            int b = blk >> 2, q = blk & 3, t0g = q * 256;
            if (q == 0 && s > 0)
                charpred(b, s - 1, h1in, ctxT, charw, charb, preds, smem);
            float* meanL = smem + 1024;   // 257 entries
            float* redD = smem + 1300;    // 256
            int* redI = (int*)redD;
            int zacc = 0;
            for (int i = tid; i < 1024; i += 256) zacc |= colZero[i];
            redI[tid] = zacc;
            __syncthreads();
            for (int o = 128; o > 0; o >>= 1) {
                if (tid < o) redI[tid] |= redI[tid + o];
                __syncthreads();
            }
            int zf = redI[0];
            __syncthreads();
            int t = t0g + tid;
            {
                float ssum = 0.f;
#pragma unroll 4
                for (int bb = 0; bb < 64; ++bb) ssum += energy[bb * 1024 + t];
                meanL[tid + 1] = ssum * (1.f / 64.f);
            }
            if (t0g > 0) {
                if (tid < 64) {
                    float v = energy[tid * 1024 + t0g - 1];
                    for (int o = 32; o > 0; o >>= 1) v += __shfl_xor(v, o, 64);
                    if (tid == 0) meanL[0] = v * (1.f / 64.f);
                }
            } else if (tid == 0) meanL[0] = 0.f;
            __syncthreads();
            float e_own = energy[b * 1024 + t];
            float a_own = (t > 0) ? energy[b * 1024 + t - 1] : 0.f;
            float rT = 0.f, dsT = 1.f;
            int badT = 0;
            if (t >= 1 && t < 1023) {
                float ma = meanL[tid], mb = meanL[tid + 1];
                float sab = 0.f, saa = 0.f, sbb = 0.f;
                bool aeq = true;
#pragma unroll 4
                for (int bb = 0; bb < 64; ++bb) {
                    float av = energy[bb * 1024 + t - 1];
                    float bv = energy[bb * 1024 + t];
                    float am = av - ma, bm = bv - mb;
                    sab = fmaf(am, bm, sab);
                    saa = fmaf(am, am, saa);
                    sbb = fmaf(bm, bm, sbb);
                    aeq = aeq && (av == bv);
                }
                float r = sab / sqrtf(saa * sbb + 1e-12f);
                float det = 1.f - r * r;
                badT = ((det < 0.01f) || aeq) ? 1 : 0;
                rT = r;
                dsT = fmaxf(det, 1e-6f);
            }
            float val;
            if (zf) {
                val = e_own;
            } else {
                float pdf = __expf(-0.5f * e_own * e_own) * INV_SQRT_2PI;
                float cp;
                if (t == 0 || t == 1023) cp = 1.f;
                else if (badT) cp = 10.f;
                else {
                    float quad = rT * rT * (a_own * a_own + e_own * e_own) - 2.f * rT * a_own * e_own;
                    cp = __expf(-0.5f * quad / dsT) / sqrtf(dsT);
                }
                val = pdf * cp;
            }
            vbuf[b * 1024 + t] = val;
            redD[tid] = val;
            __syncthreads();
            for (int o = 128; o > 0; o >>= 1) {
                if (tid < o) redD[tid] = fmaxf(redD[tid], redD[tid + o]);
                __syncthreads();
            }
            float mq = redD[0];
            __syncthreads();
            redD[tid] = __expf(val - mq);
            __syncthreads();
            for (int o = 128; o > 0; o >>= 1) {
                if (tid < o) redD[tid] += redD[tid + o];
                __syncthreads();
            }
            if (tid == 0) { pmax[b * 4 + q] = mq; psum[b * 4 + q] = redD[0]; }
        }
        gbar(bar, barTgt);

        // ---- phase D2: att finalize + context ----
        {
            int b = blk >> 2, dq = blk & 3, d0 = dq * 128;
            float* att = smem;            // 1024
            float* red2 = smem + 1024;    // 512
            float m0v = pmax[b * 4 + 0], m1v = pmax[b * 4 + 1];
            float m2v = pmax[b * 4 + 2], m3v = pmax[b * 4 + 3];
            float M = fmaxf(fmaxf(m0v, m1v), fmaxf(m2v, m3v));
            float S = psum[b * 4 + 0] * __expf(m0v - M) + psum[b * 4 + 1] * __expf(m1v - M)
                    + psum[b * 4 + 2] * __expf(m2v - M) + psum[b * 4 + 3] * __expf(m3v - M);
            float invS = 1.f / S;
            for (int i = 0; i < 4; ++i) {
                int t = tid + 256 * i;
                float av = __expf(vbuf[b * 1024 + t] - M) * invS;
                att[t] = av;
                if (dq == 0) atts[((size_t)s * B_ + b) * 1024 + t] = av;
            }
            __syncthreads();
            int lane = tid & 63, qt = tid >> 6;
            int dl = 2 * lane;
            float a0 = 0.f, a1 = 0.f;
            if (useBf) {
                const unsigned short* Lb = Lbf + ((size_t)b * 1024) * 512 + d0 + dl;
#pragma unroll 4
                for (int tt = 0; tt < 256; ++tt) {
                    int t = qt * 256 + tt;
                    float wv = att[t];
                    unsigned int v = *(const unsigned int*)(Lb + (size_t)t * 512);
                    a0 = fmaf(wv, bf2f((unsigned short)(v & 0xffff)), a0);
                    a1 = fmaf(wv, bf2f((unsigned short)(v >> 16)), a1);
                }
            } else {
                const float* Lp = Lf + ((size_t)b * 1024) * 512 + d0 + dl;
#pragma unroll 4
                for (int tt = 0; tt < 256; ++tt) {
                    int t = qt * 256 + tt;
                    float wv = att[t];
                    float2 v = *(const float2*)(Lp + (size_t)t * 512);
                    a0 = fmaf(wv, v.x, a0);
                    a1 = fmaf(wv, v.y, a1);
                }
            }
            red2[qt * 128 + dl] = a0;
            red2[qt * 128 + dl + 1] = a1;
            __syncthreads();
            if (tid < 128) {
                float ssum = red2[tid] + red2[128 + tid] + red2[256 + tid] + red2[384 + tid];
                ctxT[(d0 + tid) * 64 + b] = ssum;
            }
        }
        gbar(bar, barTgt);
    }

    // tail: char-pred for step 63 (h1 of step63 = buffer 0; ctxT from D2(63))
    if (blk < 64)
        charpred(blk, SS - 1, h1, ctxT, charw, charb, preds, smem);
}

extern "C" void kernel_launch(void* const* d_in, const int* in_sizes, int n_in,
                              void* d_out, int out_size, void* d_ws, size_t ws_size,
                              hipStream_t stream) {
    const float* Lf   = (const float*)d_in[0];
    const float* gt   = (const float*)d_in[1];
    const float* phiw = (const float*)d_in[2];
    const float* phib = (const float*)d_in[3];
    const float* psiw = (const float*)d_in[4];
    const float* psib = (const float*)d_in[5];
    const float* wih0 = (const float*)d_in[6];
    const float* whh0 = (const float*)d_in[7];
    const float* bih0 = (const float*)d_in[8];
    const float* bhh0 = (const float*)d_in[9];
    const float* wih1 = (const float*)d_in[10];
    const float* whh1 = (const float*)d_in[11];
    const float* bih1 = (const float*)d_in[12];
    const float* bhh1 = (const float*)d_in[13];
    const float* charw = (const float*)d_in[14];
    const float* charb = (const float*)d_in[15];

    float* preds = (float*)d_out;
    float* atts  = (float*)d_out + (size_t)SS * B_ * CC;

    char* ws = (char*)d_ws;
    size_t off = 0;
    auto alloc = [&](size_t bytes) { size_t o = off; off = (off + bytes + 255) & ~(size_t)255; return o; };
    unsigned short* clT = (unsigned short*)(ws + alloc((size_t)B_ * M_ * T_ * 2));
    float* gtT   = (float*)(ws + alloc((size_t)SS * CC * 64 * 4));
    float* h0    = (float*)(ws + alloc(2 * H_ * B_ * 4));
    float* c0    = (float*)(ws + alloc(H_ * B_ * 4));
    float* h1    = (float*)(ws + alloc(2 * H_ * B_ * 4));
    float* c1    = (float*)(ws + alloc(H_ * B_ * 4));
    float* h1b   = (float*)(ws + alloc(H_ * B_ * 4));
    float* ctxT  = (float*)(ws + alloc(H_ * B_ * 4));
    float* energy = (float*)(ws + alloc(B_ * T_ * 4));
    float* vbuf  = (float*)(ws + alloc(B_ * T_ * 4));
    float* pmax  = (float*)(ws + alloc(B_ * 4 * 4));
    float* psum  = (float*)(ws + alloc(B_ * 4 * 4));
    int* colZero = (int*)(ws + alloc(1024 * 4));
    int* bar     = (int*)(ws + alloc(256));
    unsigned short* psibf = (unsigned short*)(ws + alloc((size_t)M_ * D_ * 2));
    size_t baseNeed = off;
    size_t lbfBytes = (size_t)B_ * T_ * D_ * 2;
    int useBf = (baseNeed + lbfBytes + 256 <= ws_size) ? 1 : 0;
    unsigned short* Lbf = (unsigned short*)(ws + (useBf ? alloc(lbfBytes) : 0));

    hipMemsetAsync(bar, 0, 256, stream);
    if (useBf) {
        k_conv<<<2048, 256, 0, stream>>>(Lf, Lbf, (B_ * T_ * D_) / 4);
        k_conv<<<128, 256, 0, stream>>>(psiw, psibf, (M_ * D_) / 4);
        k_gemm_mfma<<<4096, 256, 0, stream>>>(Lbf, psibf, psib, clT);
    } else {
        k_gemm<<<4096, 256, 0, stream>>>(Lf, psiw, psib, clT);
    }
    k_mega<<<256, 256, 0, stream>>>(Lf, Lbf, useBf, gt,
                                    phiw, phib, wih0, whh0, bih0, bhh0,
                                    wih1, whh1, bih1, bhh1, charw, charb,
                                    clT, gtT, h0, c0, h1, c1, h1b,
                                    ctxT, energy, vbuf, pmax, psum,
                                    colZero, bar, preds, atts);
}

// Round 3
// 19975.256 us; speedup vs baseline: 1.2685x; 1.2685x over previous
//
#include <hip/hip_runtime.h>
#include <hip/hip_bf16.h>
#include <math.h>

#define B_ 64
#define T_ 1024
#define D_ 512
#define H_ 512
#define M_ 256
#define CC 63
#define SS 64
#define NBLK 512
#define INV_SQRT_2PI 0.3989422804014327f

typedef __attribute__((ext_vector_type(8))) short short8v;
typedef __attribute__((ext_vector_type(4))) float f32x4;

static __device__ __forceinline__ float bf2f(unsigned short u) {
    unsigned int x = ((unsigned int)u) << 16;
    return __uint_as_float(x);
}
static __device__ __forceinline__ unsigned short f2bf(float f) {
    unsigned int x = __float_as_uint(f);
    unsigned int r = (x + 0x7fff + ((x >> 16) & 1)) >> 16;
    return (unsigned short)r;
}
static __device__ __forceinline__ float sigm(float x) {
    return 1.f / (1.f + __expf(-x));
}
static __device__ __forceinline__ float wsum64(float v) {
    for (int o = 32; o > 0; o >>= 1) v += __shfl_xor(v, o, 64);
    return v;
}

// grid barrier: monotone counter, agent scope. bar zeroed by hipMemsetAsync per launch.
static __device__ __forceinline__ void gbar(int* bar, int& tgt) {
    tgt += NBLK;
    __syncthreads();
    if (threadIdx.x == 0) {
        __builtin_amdgcn_fence(__ATOMIC_RELEASE, "agent");
        __hip_atomic_fetch_add(bar, 1, __ATOMIC_RELAXED, __HIP_MEMORY_SCOPE_AGENT);
        while (__hip_atomic_load(bar, __ATOMIC_RELAXED, __HIP_MEMORY_SCOPE_AGENT) < tgt) {
            __builtin_amdgcn_s_sleep(4);
        }
        __builtin_amdgcn_fence(__ATOMIC_ACQUIRE, "agent");
    }
    __syncthreads();
}

// ---------------- prologue kernels ----------------

__global__ __launch_bounds__(256) void k_conv(const float* __restrict__ src,
        unsigned short* __restrict__ dst, int n4) {
    int stride = gridDim.x * 256;
    for (int i = blockIdx.x * 256 + threadIdx.x; i < n4; i += stride) {
        float4 v = ((const float4*)src)[i];
        ushort4 o;
        o.x = f2bf(v.x); o.y = f2bf(v.y); o.z = f2bf(v.z); o.w = f2bf(v.w);
        ((ushort4*)dst)[i] = o;
    }
}

// MFMA bf16 GEMM: clT[b*256+m][t] = bf16(relu(sum_d Lbf[p][d]*psibf[m][d] + psib[m]))
__global__ __launch_bounds__(256) void k_gemm_mfma(
        const unsigned short* __restrict__ Abf,
        const unsigned short* __restrict__ Bbf,
        const float* __restrict__ psib,
        unsigned short* __restrict__ clT) {
    __shared__ unsigned short As[64 * 40];
    __shared__ unsigned short Bs[64 * 40];
    __shared__ unsigned short Os[64 * 72];
    int tid = threadIdx.x;
    int p0 = (blockIdx.x >> 2) * 64;
    int m0 = (blockIdx.x & 3) * 64;
    int w = tid >> 6, l = tid & 63;
    int wp = (w & 1) * 32, wm = (w >> 1) * 32;
    f32x4 acc[2][2] = {};
    int srow = tid >> 2, sc = (tid & 3) * 8;
    for (int k0 = 0; k0 < 512; k0 += 32) {
        __syncthreads();
        *(short8v*)&As[srow * 40 + sc] = *(const short8v*)&Abf[(size_t)(p0 + srow) * 512 + k0 + sc];
        *(short8v*)&Bs[srow * 40 + sc] = *(const short8v*)&Bbf[(size_t)(m0 + srow) * 512 + k0 + sc];
        __syncthreads();
        int koff = (l >> 4) * 8;
        int rlo = l & 15;
        short8v a0 = *(short8v*)&As[(wp + rlo) * 40 + koff];
        short8v a1 = *(short8v*)&As[(wp + 16 + rlo) * 40 + koff];
        short8v b0 = *(short8v*)&Bs[(wm + rlo) * 40 + koff];
        short8v b1 = *(short8v*)&Bs[(wm + 16 + rlo) * 40 + koff];
        acc[0][0] = __builtin_amdgcn_mfma_f32_16x16x32_bf16(a0, b0, acc[0][0], 0, 0, 0);
        acc[0][1] = __builtin_amdgcn_mfma_f32_16x16x32_bf16(a0, b1, acc[0][1], 0, 0, 0);
        acc[1][0] = __builtin_amdgcn_mfma_f32_16x16x32_bf16(a1, b0, acc[1][0], 0, 0, 0);
        acc[1][1] = __builtin_amdgcn_mfma_f32_16x16x32_bf16(a1, b1, acc[1][1], 0, 0, 0);
    }
    __syncthreads();
#pragma unroll
    for (int pi = 0; pi < 2; ++pi)
#pragma unroll
        for (int mi = 0; mi < 2; ++mi)
#pragma unroll
            for (int r = 0; r < 4; ++r) {
                int tl = wp + pi * 16 + (l >> 4) * 4 + r;
                int ml = wm + mi * 16 + (l & 15);
                float v = fmaxf(acc[pi][mi][r] + psib[m0 + ml], 0.f);
                Os[ml * 72 + tl] = f2bf(v);
            }
    __syncthreads();
    int b = p0 >> 10, t0 = p0 & 1023;
    int mm = tid >> 2, c16 = (tid & 3) * 16;
    short8v v0 = *(short8v*)&Os[mm * 72 + c16];
    short8v v1 = *(short8v*)&Os[mm * 72 + c16 + 8];
    size_t base = ((size_t)(b * 256 + m0 + mm)) * 1024 + t0 + c16;
    *(short8v*)&clT[base] = v0;
    *(short8v*)&clT[base + 8] = v1;
}

// fallback f32 GEMM
__global__ __launch_bounds__(256) void k_gemm(const float* __restrict__ Lf,
        const float* __restrict__ psiw, const float* __restrict__ psib,
        unsigned short* __restrict__ clT) {
    __shared__ float At[64 * 65];
    __shared__ float Bt[64 * 65];
    int tid = threadIdx.x;
    int pt = blockIdx.x >> 2;
    int mt = blockIdx.x & 3;
    int p0 = pt * 64, m0 = mt * 64;
    int tp = tid >> 4, tm = tid & 15;
    float acc[4][4] = {{0.f}};
    for (int k0 = 0; k0 < 512; k0 += 64) {
        __syncthreads();
        for (int i = 0; i < 16; ++i) {
            int lidx = i * 256 + tid;
            int r = lidx >> 6, c = lidx & 63;
            At[r * 65 + c] = Lf[(size_t)(p0 + r) * 512 + k0 + c];
            Bt[r * 65 + c] = psiw[(size_t)(m0 + r) * 512 + k0 + c];
        }
        __syncthreads();
        for (int dk = 0; dk < 64; ++dk) {
            float av[4], bv[4];
#pragma unroll
            for (int i = 0; i < 4; ++i) av[i] = At[(4 * tp + i) * 65 + dk];
#pragma unroll
            for (int j = 0; j < 4; ++j) bv[j] = Bt[(4 * tm + j) * 65 + dk];
#pragma unroll
            for (int i = 0; i < 4; ++i)
#pragma unroll
                for (int j = 0; j < 4; ++j)
                    acc[i][j] = fmaf(av[i], bv[j], acc[i][j]);
        }
    }
#pragma unroll
    for (int i = 0; i < 4; ++i) {
        int p = p0 + 4 * tp + i;
        int b = p >> 10, t = p & 1023;
#pragma unroll
        for (int j = 0; j < 4; ++j) {
            int m = m0 + 4 * tm + j;
            float v = fmaxf(acc[i][j] + psib[m], 0.f);
            clT[((size_t)(b * 256 + m)) * 1024 + t] = f2bf(v);
        }
    }
}

// ---------------- persistent mega kernel, 512 blocks ----------------

__global__ __launch_bounds__(256, 2) void k_mega(
        const float* __restrict__ Lf, const unsigned short* __restrict__ Lbf, int useBf,
        const float* __restrict__ gt,
        const float* __restrict__ phiw, const float* __restrict__ phib,
        const float* __restrict__ wih0, const float* __restrict__ whh0,
        const float* __restrict__ bih0, const float* __restrict__ bhh0,
        const float* __restrict__ wih1, const float* __restrict__ whh1,
        const float* __restrict__ bih1, const float* __restrict__ bhh1,
        const float* __restrict__ charw, const float* __restrict__ charb,
        const unsigned short* __restrict__ clT,
        float* gtT, float* h0buf, float* h1buf, float* h1bb,
        float* ctxT, float* ctxb, float* energy, float* vbuf,
        float* cdb, float* logit, int* colZero, int* bar,
        float* preds, float* atts) {
    // LDS: pinned weights (f32) + overlay workspace + cell state/biases
    __shared__ float wA[8704];   // 8 rows x 1088: [0,575)=wih0, [575,1087)=whh0, [1087]=0
    __shared__ float wB[8192];   // 8 rows x 1024: [0,512)=wih1, [512,1024)=whh1
    __shared__ float ovl[2448];  // per-phase workspace (xsT 32x68 + ex 8x32 | concat | cd+red | att+red+red2)
    __shared__ float cst[160];   // c0[64], c1[64], biasA[8]@128, biasB[8]@136

    int tid = threadIdx.x, blk = blockIdx.x;
    int barTgt = 0;
    int rg = blk >> 1, bg = blk & 1;   // row-group (2 units), batch-half

    // ---- INIT: pinned weights + biases + state zero + global init ----
    for (int r8 = 0; r8 < 8; ++r8) {
        int j = (r8 >> 1) * 512 + rg * 2 + (r8 & 1);
        for (int k = tid; k < 1088; k += 256)
            wA[r8 * 1088 + k] = (k < 575) ? wih0[(size_t)j * 575 + k]
                              : (k < 1087) ? whh0[(size_t)j * 512 + (k - 575)] : 0.f;
        for (int k = tid; k < 1024; k += 256)
            wB[r8 * 1024 + k] = (k < 512) ? wih1[(size_t)j * 512 + k]
                                          : whh1[(size_t)j * 512 + (k - 512)];
    }
    if (tid < 8) {
        int j = (tid >> 1) * 512 + rg * 2 + (tid & 1);
        cst[128 + tid] = bih0[j] + bhh0[j];
        cst[136 + tid] = bih1[j] + bhh1[j];
    }
    if (tid < 128) cst[tid] = 0.f;
    if (blk < 64) {
        int s0 = blk;
        for (int r = tid; r < CC * 64; r += 256) {
            int k = r >> 6, b = r & 63;
            gtT[s0 * (CC * 64) + r] = gt[(b * SS + s0) * CC + k];
        }
    } else if (blk < 192) {
        int idx = (blk - 64) * 256 + tid;     // 0..32767
        h0buf[idx] = 0.f;                     // pin-0 buffers
        h1buf[idx] = 0.f;
        int d = idx >> 6, b = idx & 63;
        float v = Lf[(size_t)b * (T_ * D_) + d];
        ctxT[idx] = v;
        ctxb[b * 512 + d] = v;
    }
    gbar(bar, barTgt);

    int bl = tid & 31, r8 = tid >> 5;

    for (int s = 0; s < SS; ++s) {
        int pin = s & 1;
        const float* h0in = h0buf + pin * 32768;
        float* h0out = h0buf + (1 - pin) * 32768;
        const float* h1in = h1buf + pin * 32768;
        float* h1out = h1buf + (1 - pin) * 32768;
        const float* h1b_prev = h1bb + pin * 32768;
        float* h1b_cur = h1bb + (1 - pin) * 32768;

        // ---- phase A: LSTM0 (units rg*2+{0,1}, batch half bg) ----
        {
            f32x4 a4 = {0.f, 0.f, 0.f, 0.f};
            for (int kc = 0; kc < 17; ++kc) {
                __syncthreads();
                int k0 = kc * 64;
#pragma unroll
                for (int i = 0; i < 8; ++i) {
                    int lidx = i * 256 + tid;
                    int dk = lidx >> 5, bcol = lidx & 31;
                    int k = k0 + dk;
                    int b = bg * 32 + bcol;
                    float v;
                    if (k < 63)        v = (s > 0) ? gtT[(s - 1) * 4032 + k * 64 + b] : ((k == 0) ? 1.f : 0.f);
                    else if (k < 575)  v = ctxT[(k - 63) * 64 + b];
                    else if (k < 1087) v = h0in[(k - 575) * 64 + b];
                    else               v = 0.f;
                    ovl[bcol * 68 + dk] = v;
                }
                __syncthreads();
                const float4* xr = (const float4*)&ovl[bl * 68];
                const float4* wr = (const float4*)&wA[r8 * 1088 + k0];
#pragma unroll
                for (int q = 0; q < 16; ++q) {
                    float4 x4 = xr[q];
                    float4 w4 = wr[q];
                    a4.x = fmaf(x4.x, w4.x, a4.x);
                    a4.y = fmaf(x4.y, w4.y, a4.y);
                    a4.z = fmaf(x4.z, w4.z, a4.z);
                    a4.w = fmaf(x4.w, w4.w, a4.w);
                }
            }
            float acc = a4.x + a4.y + a4.z + a4.w + cst[128 + r8];
            float* ex = ovl + 2176;
            __syncthreads();
            ex[r8 * 32 + bl] = acc;
            __syncthreads();
            if (tid < 64) {
                int ui = tid >> 5, b32 = tid & 31;
                float gi = ex[(0 + ui) * 32 + b32];
                float gf = ex[(2 + ui) * 32 + b32];
                float gg = ex[(4 + ui) * 32 + b32];
                float go = ex[(6 + ui) * 32 + b32];
                float cv = cst[ui * 32 + b32];
                float cn = sigm(gf) * cv + sigm(gi) * tanhf(gg);
                float hn = sigm(go) * tanhf(cn);
                cst[ui * 32 + b32] = cn;
                int u = rg * 2 + ui;
                h0out[u * 64 + bg * 32 + b32] = hn;
            }
        }
        gbar(bar, barTgt);

        // ---- phase B: LSTM1 ----
        {
            f32x4 a4 = {0.f, 0.f, 0.f, 0.f};
            for (int kc = 0; kc < 16; ++kc) {
                __syncthreads();
                int k0 = kc * 64;
#pragma unroll
                for (int i = 0; i < 8; ++i) {
                    int lidx = i * 256 + tid;
                    int dk = lidx >> 5, bcol = lidx & 31;
                    int k = k0 + dk;
                    int b = bg * 32 + bcol;
                    float v = (k < 512) ? h0out[k * 64 + b] : h1in[(k - 512) * 64 + b];
                    ovl[bcol * 68 + dk] = v;
                }
                __syncthreads();
                const float4* xr = (const float4*)&ovl[bl * 68];
                const float4* wr = (const float4*)&wB[r8 * 1024 + k0];
#pragma unroll
                for (int q = 0; q < 16; ++q) {
                    float4 x4 = xr[q];
                    float4 w4 = wr[q];
                    a4.x = fmaf(x4.x, w4.x, a4.x);
                    a4.y = fmaf(x4.y, w4.y, a4.y);
                    a4.z = fmaf(x4.z, w4.z, a4.z);
                    a4.w = fmaf(x4.w, w4.w, a4.w);
                }
            }
            float acc = a4.x + a4.y + a4.z + a4.w + cst[136 + r8];
            float* ex = ovl + 2176;
            __syncthreads();
            ex[r8 * 32 + bl] = acc;
            __syncthreads();
            if (tid < 64) {
                int ui = tid >> 5, b32 = tid & 31;
                float gi = ex[(0 + ui) * 32 + b32];
                float gf = ex[(2 + ui) * 32 + b32];
                float gg = ex[(4 + ui) * 32 + b32];
                float go = ex[(6 + ui) * 32 + b32];
                float cv = cst[64 + ui * 32 + b32];
                float cn = sigm(gf) * cv + sigm(gi) * tanhf(gg);
                float hn = sigm(go) * tanhf(cn);
                cst[64 + ui * 32 + b32] = cn;
                int u = rg * 2 + ui;
                int b = bg * 32 + b32;
                h1out[u * 64 + b] = hn;
                h1b_cur[b * 512 + u] = hn;
            }
        }
        gbar(bar, barTgt);

        // ---- phase C: char-logits(s-1) + phi comp_dec + colZero init ----
        {
            if (s > 0) {
                int b_cp = blk >> 3;
                for (int i = tid; i < 1024; i += 256)
                    ovl[i] = (i < 512) ? h1b_prev[b_cp * 512 + i] : ctxb[b_cp * 512 + (i - 512)];
                __syncthreads();
                int c8 = tid >> 5, kl = tid & 31;
                int c = (blk & 7) * 8 + c8;
                float p = 0.f;
                if (c < 63) {
                    const float4* cw = (const float4*)&charw[(size_t)c * 1024 + kl * 32];
                    const float4* cc = (const float4*)&ovl[kl * 32];
#pragma unroll
                    for (int q = 0; q < 8; ++q) {
                        float4 w4 = cw[q], x4 = cc[q];
                        p = fmaf(x4.x, w4.x, p); p = fmaf(x4.y, w4.y, p);
                        p = fmaf(x4.z, w4.z, p); p = fmaf(x4.w, w4.w, p);
                    }
                }
                p += __shfl_xor(p, 1, 64); p += __shfl_xor(p, 2, 64);
                p += __shfl_xor(p, 4, 64); p += __shfl_xor(p, 8, 64);
                p += __shfl_xor(p, 16, 64);
                if (kl == 0 && c < 63) logit[b_cp * 64 + c] = p + charb[c];
            }
            // phi: block = (mg 32) x (bgp 16); thread = (m8, b4, kg)
            int mg = blk >> 4, bgp = blk & 15;
            int m8 = tid >> 5, b4 = (tid >> 3) & 3, kg = tid & 7;
            int m = mg * 8 + m8, b = bgp * 4 + b4;
            float p = 0.f;
            const float4* wr = (const float4*)&phiw[(size_t)m * 512 + kg * 64];
            const float4* xr = (const float4*)&h1b_cur[b * 512 + kg * 64];
#pragma unroll
            for (int q = 0; q < 16; ++q) {
                float4 w4 = wr[q], x4 = xr[q];
                p = fmaf(x4.x, w4.x, p); p = fmaf(x4.y, w4.y, p);
                p = fmaf(x4.z, w4.z, p); p = fmaf(x4.w, w4.w, p);
            }
            p += __shfl_xor(p, 1, 64); p += __shfl_xor(p, 2, 64); p += __shfl_xor(p, 4, 64);
            if (kg == 0) cdb[b * 256 + m] = fmaxf(p + phib[m], 0.f);
            if (blk == 0)
                for (int i = tid; i < 1024; i += 256) colZero[i] = 1;
        }
        gbar(bar, barTgt);

        // ---- phase D: energy (b x 8 t-chunks) + preds-write(s-1) ----
        {
            int b = blk >> 3, tc = blk & 7, t0 = tc * 128;
            float* cdl = ovl;
            float* redp = ovl + 256;
            cdl[tid] = cdb[b * 256 + tid];
            __syncthreads();
            int tl = tid & 127, kh = tid >> 7;
            const unsigned short* base = clT + ((size_t)(b * 256 + kh * 128)) * 1024 + t0 + tl;
            float e = 0.f;
#pragma unroll 16
            for (int m = 0; m < 128; ++m)
                e = fmaf(cdl[kh * 128 + m], bf2f(base[(size_t)m * 1024]), e);
            redp[tid] = e;
            __syncthreads();
            if (tid < 128) {
                float sum = redp[tid] + redp[128 + tid];
                energy[b * 1024 + t0 + tid] = sum;
                if (sum != 0.f) colZero[t0 + tid] = 0;
            }
            if (tc == 0 && s > 0 && tid < 64) {
                int c = tid;
                float lg = (c < 63) ? logit[b * 64 + c] : -1e30f;
                float mx = lg;
                for (int o = 32; o > 0; o >>= 1) mx = fmaxf(mx, __shfl_xor(mx, o, 64));
                float ex2 = (c < 63) ? __expf(lg - mx) : 0.f;
                float sume = wsum64(ex2);
                if (c < 63)
                    preds[((size_t)(s - 1) * B_ + b) * CC + c] = lg - mx - __logf(sume);
            }
        }
        gbar(bar, barTgt);

        // ---- phase E: copula stats + vals (blocks 0..255, 4 t per block) ----
        {
            int* zred = (int*)ovl;
            if (blk < 256) {
                int zacc = colZero[tid] | colZero[256 + tid] | colZero[512 + tid] | colZero[768 + tid];
                zred[tid] = zacc;
                __syncthreads();
                for (int o = 128; o > 0; o >>= 1) {
                    if (tid < o) zred[tid] |= zred[tid + o];
                    __syncthreads();
                }
                int zf = zred[0];
                int wv = tid >> 6, b = tid & 63;
                int t = blk * 4 + wv;
                float e = energy[b * 1024 + t];
                float a = (t > 0) ? energy[b * 1024 + t - 1] : 0.f;
                float val;
                if (zf) {
                    val = e;
                } else {
                    float cp;
                    if (t >= 1 && t < 1023) {
                        float ma = wsum64(a) * (1.f / 64.f);
                        float mb = wsum64(e) * (1.f / 64.f);
                        float am = a - ma, bm = e - mb;
                        float sab = wsum64(am * bm);
                        float saa = wsum64(am * am);
                        float sbb = wsum64(bm * bm);
                        int aeq = __all(a == e);
                        float r = sab / sqrtf(saa * sbb + 1e-12f);
                        float det = 1.f - r * r;
                        if (det < 0.01f || aeq) cp = 10.f;
                        else {
                            float ds = fmaxf(det, 1e-6f);
                            float quad = r * r * (a * a + e * e) - 2.f * r * a * e;
                            cp = __expf(-0.5f * quad / ds) / sqrtf(ds);
                        }
                    } else {
                        cp = 1.f;
                    }
                    float pdf = __expf(-0.5f * e * e) * INV_SQRT_2PI;
                    val = pdf * cp;
                }
                vbuf[b * 1024 + t] = val;
            }
        }
        gbar(bar, barTgt);

        // ---- phase F: softmax + atts + context (b x 8 d-chunks of 64) ----
        {
            int b = blk >> 3, dq = blk & 7, d0 = dq * 64;
            float* att = ovl;
            float* red = ovl + 1024;
            float* red2 = ovl + 1280;
            float4 v4 = *(const float4*)&vbuf[b * 1024 + tid * 4];
            float lm = fmaxf(fmaxf(v4.x, v4.y), fmaxf(v4.z, v4.w));
            red[tid] = lm;
            __syncthreads();
            for (int o = 128; o > 0; o >>= 1) {
                if (tid < o) red[tid] = fmaxf(red[tid], red[tid + o]);
                __syncthreads();
            }
            float M = red[0];
            __syncthreads();
            float e0 = __expf(v4.x - M), e1 = __expf(v4.y - M);
            float e2 = __expf(v4.z - M), e3 = __expf(v4.w - M);
            red[tid] = e0 + e1 + e2 + e3;
            __syncthreads();
            for (int o = 128; o > 0; o >>= 1) {
                if (tid < o) red[tid] += red[tid + o];
                __syncthreads();
            }
            float inv = 1.f / red[0];
            float4 a4 = make_float4(e0 * inv, e1 * inv, e2 * inv, e3 * inv);
            *(float4*)&att[tid * 4] = a4;
            if (dq == 0)
                *(float4*)&atts[((size_t)s * B_ + b) * 1024 + tid * 4] = a4;
            __syncthreads();
            int dl = tid & 63, qt = tid >> 6;
            float a = 0.f;
            if (useBf) {
                const unsigned short* Lb = Lbf + (size_t)b * 524288 + (size_t)(qt * 256) * 512 + d0 + dl;
#pragma unroll 8
                for (int tt = 0; tt < 256; ++tt)
                    a = fmaf(att[qt * 256 + tt], bf2f(Lb[(size_t)tt * 512]), a);
            } else {
                const float* Lp = Lf + (size_t)b * 524288 + (size_t)(qt * 256) * 512 + d0 + dl;
#pragma unroll 8
                for (int tt = 0; tt < 256; ++tt)
                    a = fmaf(att[qt * 256 + tt], Lp[(size_t)tt * 512], a);
            }
            red2[qt * 64 + dl] = a;
            __syncthreads();
            if (tid < 64) {
                float cv = red2[tid] + red2[64 + tid] + red2[128 + tid] + red2[192 + tid];
                ctxT[(d0 + tid) * 64 + b] = cv;
                ctxb[b * 512 + d0 + tid] = cv;
            }
        }
        gbar(bar, barTgt);
    }

    // ---- tail: char-logits + preds for s=63 (h1b of step 63 is buffer 0) ----
    {
        int b_cp = blk >> 3;
        for (int i = tid; i < 1024; i += 256)
            ovl[i] = (i < 512) ? h1bb[b_cp * 512 + i] : ctxb[b_cp * 512 + (i - 512)];
        __syncthreads();
        int c8 = tid >> 5, kl = tid & 31;
        int c = (blk & 7) * 8 + c8;
        float p = 0.f;
        if (c < 63) {
            const float4* cw = (const float4*)&charw[(size_t)c * 1024 + kl * 32];
            const float4* cc = (const float4*)&ovl[kl * 32];
#pragma unroll
            for (int q = 0; q < 8; ++q) {
                float4 w4 = cw[q], x4 = cc[q];
                p = fmaf(x4.x, w4.x, p); p = fmaf(x4.y, w4.y, p);
                p = fmaf(x4.z, w4.z, p); p = fmaf(x4.w, w4.w, p);
            }
        }
        p += __shfl_xor(p, 1, 64); p += __shfl_xor(p, 2, 64);
        p += __shfl_xor(p, 4, 64); p += __shfl_xor(p, 8, 64);
        p += __shfl_xor(p, 16, 64);
        if (kl == 0 && c < 63) logit[b_cp * 64 + c] = p + charb[c];
    }
    gbar(bar, barTgt);
    if (blk < 64 && tid < 64) {
        int b = blk, c = tid;
        float lg = (c < 63) ? logit[b * 64 + c] : -1e30f;
        float mx = lg;
        for (int o = 32; o > 0; o >>= 1) mx = fmaxf(mx, __shfl_xor(mx, o, 64));
        float ex2 = (c < 63) ? __expf(lg - mx) : 0.f;
        float sume = wsum64(ex2);
        if (c < 63)
            preds[((size_t)(SS - 1) * B_ + b) * CC + c] = lg - mx - __logf(sume);
    }
}

extern "C" void kernel_launch(void* const* d_in, const int* in_sizes, int n_in,
                              void* d_out, int out_size, void* d_ws, size_t ws_size,
                              hipStream_t stream) {
    const float* Lf   = (const float*)d_in[0];
    const float* gt   = (const float*)d_in[1];
    const float* phiw = (const float*)d_in[2];
    const float* phib = (const float*)d_in[3];
    const float* psiw = (const float*)d_in[4];
    const float* psib = (const float*)d_in[5];
    const float* wih0 = (const float*)d_in[6];
    const float* whh0 = (const float*)d_in[7];
    const float* bih0 = (const float*)d_in[8];
    const float* bhh0 = (const float*)d_in[9];
    const float* wih1 = (const float*)d_in[10];
    const float* whh1 = (const float*)d_in[11];
    const float* bih1 = (const float*)d_in[12];
    const float* bhh1 = (const float*)d_in[13];
    const float* charw = (const float*)d_in[14];
    const float* charb = (const float*)d_in[15];

    float* preds = (float*)d_out;
    float* atts  = (float*)d_out + (size_t)SS * B_ * CC;

    char* ws = (char*)d_ws;
    size_t off = 0;
    auto alloc = [&](size_t bytes) { size_t o = off; off = (off + bytes + 255) & ~(size_t)255; return o; };
    unsigned short* clT = (unsigned short*)(ws + alloc((size_t)B_ * M_ * T_ * 2));
    float* gtT    = (float*)(ws + alloc((size_t)SS * CC * 64 * 4));
    float* h0buf  = (float*)(ws + alloc(2 * H_ * B_ * 4));
    float* h1buf  = (float*)(ws + alloc(2 * H_ * B_ * 4));
    float* h1bb   = (float*)(ws + alloc(2 * H_ * B_ * 4));
    float* ctxT   = (float*)(ws + alloc(H_ * B_ * 4));
    float* ctxb   = (float*)(ws + alloc(H_ * B_ * 4));
    float* energy = (float*)(ws + alloc(B_ * T_ * 4));
    float* vbuf   = (float*)(ws + alloc(B_ * T_ * 4));
    float* cdb    = (float*)(ws + alloc(B_ * M_ * 4));
    float* logit  = (float*)(ws + alloc(B_ * 64 * 4));
    int* colZero  = (int*)(ws + alloc(1024 * 4));
    int* bar      = (int*)(ws + alloc(256));
    unsigned short* psibf = (unsigned short*)(ws + alloc((size_t)M_ * D_ * 2));
    size_t baseNeed = off;
    size_t lbfBytes = (size_t)B_ * T_ * D_ * 2;
    int useBf = (baseNeed + lbfBytes + 256 <= ws_size) ? 1 : 0;
    unsigned short* Lbf = (unsigned short*)(ws + (useBf ? alloc(lbfBytes) : 0));

    hipMemsetAsync(bar, 0, 256, stream);
    if (useBf) {
        k_conv<<<2048, 256, 0, stream>>>(Lf, Lbf, (B_ * T_ * D_) / 4);
        k_conv<<<128, 256, 0, stream>>>(psiw, psibf, (M_ * D_) / 4);
        k_gemm_mfma<<<4096, 256, 0, stream>>>(Lbf, psibf, psib, clT);
    } else {
        k_gemm<<<4096, 256, 0, stream>>>(Lf, psiw, psib, clT);
    }
    k_mega<<<NBLK, 256, 0, stream>>>(Lf, Lbf, useBf, gt,
                                     phiw, phib, wih0, whh0, bih0, bhh0,
                                     wih1, whh1, bih1, bhh1, charw, charb,
                                     clT, gtT, h0buf, h1buf, h1bb,
                                     ctxT, ctxb, energy, vbuf,
                                     cdb, logit, colZero, bar, preds, atts);
}